// Round 4
// baseline (346.289 us; speedup 1.0000x reference)
//
#include <hip/hip_runtime.h>
#include <stdint.h>
#include <float.h>

#define BLK 256
#define IPT 8                  // owner points per thread (8 independent min-chains)
#define OWNERS (BLK * IPT)     // 2048 owners per block / per chunk
#define SLICE 128              // scanned points per block (2 KB LDS) — r0 geometry
#define SUB 64                 // subtile granularity for deferred-index recovery

typedef unsigned long long ull;
typedef unsigned int u32;

// Monotone float -> uint transform (preserves <, total order) and inverse.
__device__ __forceinline__ unsigned int ford(float f) {
    int b = __float_as_int(f);
    return (b >= 0) ? ((unsigned)b ^ 0x80000000u) : ~(unsigned)b;
}
__device__ __forceinline__ float ford_inv(unsigned int u) {
    int b = (u & 0x80000000u) ? (int)(u ^ 0x80000000u) : (int)~u;
    return __int_as_float(b);
}

// Single fused dispatch (plus one 330 KB memset):
//   - phase 1 is bit-identical to the verified 45.7 µs kernel (SLICE=128,
//     2048 blocks, per-64-pt subtile base tracking, u64 atomicMin merge).
//   - last block per owner-chunk (device-scope counter, 0xFF-init trick:
//     counters start at -1, last arriver sees old == nSlices-2) finalizes its
//     chunk's 2048 owners in-dispatch: coherent min load + verified branchless
//     bit-exact 64-pt rescan + normal dot + block reduction.
//   - chunk sums -> ws; globally-last finisher (second 0xFF counter) sums the
//     20 chunk sums and plain-stores d_out (no d_out memset dispatch).
__global__ __launch_bounds__(BLK) void nn_fused(
    const float* __restrict__ p, const float* __restrict__ g,
    const float* __restrict__ pn, const float* __restrict__ gn,
    ull* __restrict__ mins, u32* __restrict__ ctr, u32* __restrict__ done,
    float* __restrict__ csum, float* __restrict__ out, int N, int M)
{
    __shared__ float4 sb[SLICE];
    __shared__ u32 lastFlag;
    __shared__ float partial[BLK / 64];

    const int rowSlices = M / SLICE;              // 256
    const int colSlices = N / SLICE;              // 64
    const int rowChunks = N / OWNERS;             // 4
    const int rowBlocks = rowChunks * rowSlices;  // 1024
    const int nChunks = rowChunks + (M / OWNERS); // 20

    const float* A; const float* B; const float* An; const float* Bn;
    ull* minsSide; int id, nSlices; float inv;
    const bool rowSide = (int)blockIdx.x < rowBlocks;
    if (rowSide) {
        id = blockIdx.x;             A = p; B = g; An = pn; Bn = gn;
        minsSide = mins;     nSlices = rowSlices; inv = 1.0f / (float)N;
    } else {
        id = blockIdx.x - rowBlocks; A = g; B = p; An = gn; Bn = pn;
        minsSide = mins + N; nSlices = colSlices; inv = 1.0f / (float)M;
    }
    const int chunk = id / nSlices;
    const int slice = id - chunk * nSlices;
    const int chunkG = rowSide ? chunk : (rowChunks + chunk);
    const int s0 = slice * SLICE;

    // ---- phase 1 (bit-identical to verified r0 kernel) ----
    if (threadIdx.x < SLICE) {
        int s = s0 + threadIdx.x;
        float bx = B[3 * s], by = B[3 * s + 1], bz = B[3 * s + 2];
        float w = fmaf(bz, bz, fmaf(by, by, bx * bx));
        sb[threadIdx.x] = make_float4(bx, by, bz, w);
    }

    const int o0 = chunk * OWNERS + threadIdx.x;
    float ax[IPT], ay[IPT], az[IPT], best[IPT];
    int base[IPT];
#pragma unroll
    for (int r = 0; r < IPT; ++r) {
        int o = o0 + r * BLK;
        ax[r] = -2.0f * A[3 * o];
        ay[r] = -2.0f * A[3 * o + 1];
        az[r] = -2.0f * A[3 * o + 2];
        best[r] = FLT_MAX;
        base[r] = s0;
    }
    __syncthreads();

    for (int st = 0; st < SLICE; st += SUB) {
        float prev[IPT];
#pragma unroll
        for (int r = 0; r < IPT; ++r) prev[r] = best[r];
#pragma unroll 2
        for (int k = st; k < st + SUB; k += 2) {
            float4 q0 = sb[k];        // wave-uniform broadcast reads
            float4 q1 = sb[k + 1];
#pragma unroll
            for (int r = 0; r < IPT; ++r) {
                float v0 = fmaf(ax[r], q0.x, fmaf(ay[r], q0.y, fmaf(az[r], q0.z, q0.w)));
                float v1 = fmaf(ax[r], q1.x, fmaf(ay[r], q1.y, fmaf(az[r], q1.z, q1.w)));
                best[r] = fminf(fminf(v0, v1), best[r]);   // -> v_min3_f32
            }
        }
#pragma unroll
        for (int r = 0; r < IPT; ++r)
            if (best[r] < prev[r]) base[r] = s0 + st;   // strict <: first subtile wins
    }

#pragma unroll
    for (int r = 0; r < IPT; ++r) {
        ull packed = ((ull)ford(best[r]) << 32) | (unsigned)base[r];
        atomicMin(&minsSide[o0 + r * BLK], packed);   // device-scope, coherent point
    }

    // ---- last-block detection for this chunk ----
    __syncthreads();                       // all threads' atomicMins issued
    if (threadIdx.x == 0) {
        __threadfence();                   // order our mins before the arrival
        u32 old = atomicAdd(&ctr[chunkG], 1u);       // ctr init = 0xFFFFFFFF (-1)
        lastFlag = (old == (u32)(nSlices - 2)) ? 1u : 0u;  // last of nSlices arrivals
    }
    __syncthreads();
    if (!lastFlag) return;
    __threadfence();                       // acquire: other blocks' mins visible

    // ---- in-dispatch finalize of this chunk's OWNERS owners ----
    float c = 0.0f;
#pragma unroll
    for (int r = 0; r < IPT; ++r) {
        int o = chunk * OWNERS + threadIdx.x + r * BLK;
        // agent-scope load: bypass potentially-stale L1/L2 (written by other XCDs)
        ull packed = __hip_atomic_load(&minsSide[o], __ATOMIC_RELAXED,
                                       __HIP_MEMORY_SCOPE_AGENT);
        float axx = -2.0f * A[3 * o];
        float ayy = -2.0f * A[3 * o + 1];
        float azz = -2.0f * A[3 * o + 2];
        float bestf = ford_inv((unsigned int)(packed >> 32));
        int b0 = (int)(packed & 0xffffffffull);

        // Branchless bit-exact first-match rescan (verified absmax=0 path).
        int idx = 0x7fffffff;
#pragma unroll 4
        for (int jj = 0; jj < SUB; ++jj) {
            int s = b0 + jj;
            float bx = B[3 * s], by = B[3 * s + 1], bz = B[3 * s + 2];
            float w = fmaf(bz, bz, fmaf(by, by, bx * bx));
            float v = fmaf(axx, bx, fmaf(ayy, by, fmaf(azz, bz, w)));
            int cand = (v == bestf) ? s : 0x7fffffff;
            idx = (cand < idx) ? cand : idx;     // ascending -> first match = min s
        }
        if (idx == 0x7fffffff) idx = b0;         // defensive; cannot trigger

        float d = An[3 * o] * Bn[3 * idx] + An[3 * o + 1] * Bn[3 * idx + 1]
                + An[3 * o + 2] * Bn[3 * idx + 2];
        c += (1.0f - d) * inv;
    }

#pragma unroll
    for (int off = 32; off > 0; off >>= 1) c += __shfl_down(c, off, 64);
    if ((threadIdx.x & 63) == 0) partial[threadIdx.x >> 6] = c;
    __syncthreads();
    if (threadIdx.x == 0) {
        float s = 0.0f;
#pragma unroll
        for (int w = 0; w < BLK / 64; ++w) s += partial[w];
        __hip_atomic_store(&csum[chunkG], s, __ATOMIC_RELAXED, __HIP_MEMORY_SCOPE_AGENT);
        __threadfence();                                   // csum before done arrival
        u32 od = atomicAdd(done, 1u);                      // done init = -1
        if (od == (u32)(nChunks - 2)) {                    // globally last finisher
            __threadfence();
            float tot = 0.0f;
            for (int k2 = 0; k2 < nChunks; ++k2)
                tot += __hip_atomic_load(&csum[k2], __ATOMIC_RELAXED,
                                         __HIP_MEMORY_SCOPE_AGENT);
            *out = tot;                                    // kernel-end release -> host
        }
    }
}

// ======================= legacy fallback (verified r0 path) =======================
__global__ __launch_bounds__(BLK) void nn_min_dual(
    const float* __restrict__ p, const float* __restrict__ g,
    ull* __restrict__ rowmin, ull* __restrict__ colmin,
    int rowBlocks, int rowSlices, int colSlices)
{
    __shared__ float4 sb[SLICE];
    const float* A; const float* B; ull* outmin; int id, nSlices;
    if ((int)blockIdx.x < rowBlocks) {
        id = blockIdx.x;             A = p; B = g; outmin = rowmin; nSlices = rowSlices;
    } else {
        id = blockIdx.x - rowBlocks; A = g; B = p; outmin = colmin; nSlices = colSlices;
    }
    const int chunk = id / nSlices;
    const int slice = id - chunk * nSlices;
    const int s0 = slice * SLICE;
    if (threadIdx.x < SLICE) {
        int s = s0 + threadIdx.x;
        float bx = B[3 * s], by = B[3 * s + 1], bz = B[3 * s + 2];
        float w = fmaf(bz, bz, fmaf(by, by, bx * bx));
        sb[threadIdx.x] = make_float4(bx, by, bz, w);
    }
    const int o0 = chunk * OWNERS + threadIdx.x;
    float ax[IPT], ay[IPT], az[IPT], best[IPT];
    int base[IPT];
#pragma unroll
    for (int r = 0; r < IPT; ++r) {
        int o = o0 + r * BLK;
        ax[r] = -2.0f * A[3 * o]; ay[r] = -2.0f * A[3 * o + 1]; az[r] = -2.0f * A[3 * o + 2];
        best[r] = FLT_MAX; base[r] = s0;
    }
    __syncthreads();
    for (int st = 0; st < SLICE; st += SUB) {
        float prev[IPT];
#pragma unroll
        for (int r = 0; r < IPT; ++r) prev[r] = best[r];
#pragma unroll 2
        for (int k = st; k < st + SUB; k += 2) {
            float4 q0 = sb[k]; float4 q1 = sb[k + 1];
#pragma unroll
            for (int r = 0; r < IPT; ++r) {
                float v0 = fmaf(ax[r], q0.x, fmaf(ay[r], q0.y, fmaf(az[r], q0.z, q0.w)));
                float v1 = fmaf(ax[r], q1.x, fmaf(ay[r], q1.y, fmaf(az[r], q1.z, q1.w)));
                best[r] = fminf(fminf(v0, v1), best[r]);
            }
        }
#pragma unroll
        for (int r = 0; r < IPT; ++r)
            if (best[r] < prev[r]) base[r] = s0 + st;
    }
#pragma unroll
    for (int r = 0; r < IPT; ++r) {
        ull packed = ((ull)ford(best[r]) << 32) | (unsigned)base[r];
        atomicMin(&outmin[o0 + r * BLK], packed);
    }
}

__global__ __launch_bounds__(BLK) void finalize_legacy(
    const ull* __restrict__ rowmin, const ull* __restrict__ colmin,
    const float* __restrict__ p, const float* __restrict__ g,
    const float* __restrict__ pn, const float* __restrict__ gn,
    float* __restrict__ out, int N, int M, float invN, float invM)
{
    int t = blockIdx.x * BLK + threadIdx.x;
    float c = 0.0f;
    if (t < N + M) {
        const float* A; const float* B; const float* An; const float* Bn;
        ull packed; int o; float inv;
        if (t < N) { o = t;     A = p; B = g; An = pn; Bn = gn; packed = rowmin[o]; inv = invN; }
        else       { o = t - N; A = g; B = p; An = gn; Bn = pn; packed = colmin[o]; inv = invM; }
        float ax = -2.0f * A[3 * o], ay = -2.0f * A[3 * o + 1], az = -2.0f * A[3 * o + 2];
        float bestf = ford_inv((unsigned int)(packed >> 32));
        int b0 = (int)(packed & 0xffffffffull);
        int idx = 0x7fffffff;
#pragma unroll 4
        for (int jj = 0; jj < SUB; ++jj) {
            int s = b0 + jj;
            float bx = B[3 * s], by = B[3 * s + 1], bz = B[3 * s + 2];
            float w = fmaf(bz, bz, fmaf(by, by, bx * bx));
            float v = fmaf(ax, bx, fmaf(ay, by, fmaf(az, bz, w)));
            int cand = (v == bestf) ? s : 0x7fffffff;
            idx = (cand < idx) ? cand : idx;
        }
        if (idx == 0x7fffffff) idx = b0;
        float d = An[3 * o] * Bn[3 * idx] + An[3 * o + 1] * Bn[3 * idx + 1]
                + An[3 * o + 2] * Bn[3 * idx + 2];
        c = (1.0f - d) * inv;
    }
#pragma unroll
    for (int off = 32; off > 0; off >>= 1) c += __shfl_down(c, off, 64);
    __shared__ float partial[BLK / 64];
    if ((threadIdx.x & 63) == 0) partial[threadIdx.x >> 6] = c;
    __syncthreads();
    if (threadIdx.x == 0) {
        float s = 0.0f;
#pragma unroll
        for (int w = 0; w < BLK / 64; ++w) s += partial[w];
        atomicAdd(out, s);
    }
}

extern "C" void kernel_launch(void* const* d_in, const int* in_sizes, int n_in,
                              void* d_out, int out_size, void* d_ws, size_t ws_size,
                              hipStream_t stream) {
    const float* p  = (const float*)d_in[0];   // [N,3] predicted points
    const float* pn = (const float*)d_in[1];   // [N,3] predicted normals (unit)
    const float* g  = (const float*)d_in[2];   // [M,3] gt points
    const float* gn = (const float*)d_in[3];   // [M,3] gt normals (unit)
    const int N = in_sizes[0] / 3;             // 8192
    const int M = in_sizes[2] / 3;             // 32768
    float* out = (float*)d_out;

    const int rowSlices = M / SLICE;           // 256
    const int colSlices = N / SLICE;           // 64
    const int rowChunks = N / OWNERS;          // 4
    const int colChunks = M / OWNERS;          // 16
    const int nChunks = rowChunks + colChunks; // 20

    // ws layout: mins[N+M] | ctr[nChunks] | done[1] | csum[nChunks]
    const size_t minsBytes = (size_t)(N + M) * sizeof(ull);
    const size_t initBytes = minsBytes + (size_t)(nChunks + 1) * sizeof(u32);   // 0xFF region
    const size_t needBytes = initBytes + (size_t)nChunks * sizeof(float);

    const bool geomOK = (N % OWNERS) == 0 && (M % OWNERS) == 0 &&
                        (N % SLICE) == 0 && (M % SLICE) == 0 &&
                        rowSlices >= 2 && colSlices >= 2 && nChunks >= 2;

    if (geomOK && ws_size >= needBytes) {
        // -------- primary: 2 dispatches (tiny memset + fused kernel) --------
        ull* mins = (ull*)d_ws;
        u32* ctr  = (u32*)((char*)d_ws + minsBytes);
        u32* done = ctr + nChunks;
        float* csum = (float*)(done + 1);
        hipMemsetAsync(d_ws, 0xFF, initBytes, stream);   // mins=+inf packed, counters=-1
        const int blocks = rowChunks * rowSlices + colChunks * colSlices;   // 2048
        nn_fused<<<blocks, BLK, 0, stream>>>(
            p, g, pn, gn, mins, ctr, done, csum, out, N, M);
    } else {
        // -------- legacy verified 4-dispatch path --------
        ull* rowmin = (ull*)d_ws;
        ull* colmin = rowmin + N;
        hipMemsetAsync(d_ws, 0xFF, (size_t)(N + M) * sizeof(ull), stream);
        hipMemsetAsync(d_out, 0, sizeof(float), stream);
        const int rowBlocks = rowChunks * rowSlices;
        const int colBlocks = colChunks * colSlices;
        nn_min_dual<<<rowBlocks + colBlocks, BLK, 0, stream>>>(
            p, g, rowmin, colmin, rowBlocks, rowSlices, colSlices);
        int tot = N + M;
        finalize_legacy<<<(tot + BLK - 1) / BLK, BLK, 0, stream>>>(
            rowmin, colmin, p, g, pn, gn, out, N, M, 1.0f / N, 1.0f / M);
    }
}

// Round 5
// 116.002 us; speedup vs baseline: 2.9852x; 2.9852x over previous
//
#include <hip/hip_runtime.h>
#include <stdint.h>
#include <float.h>

#define BLK 256
#define IPT 8                  // owner points per thread (8 independent min-chains)
#define OWNERS (BLK * IPT)     // 2048 owners per block / per chunk
#define SLICE 128              // scanned points per block (2 KB LDS)
#define SUB 64                 // subtile granularity for deferred-index recovery
#define FBLK 64                // finalize block size (1 wave) -> 640 blocks

typedef unsigned long long ull;
typedef float v2f __attribute__((ext_vector_type(2)));

__device__ __forceinline__ v2f fma2(v2f a, v2f b, v2f c) {
    return __builtin_elementwise_fma(a, b, c);   // -> v_pk_fma_f32 (IEEE fma/half)
}

// Monotone float -> uint transform (preserves <, total order) and inverse.
__device__ __forceinline__ unsigned int ford(float f) {
    int b = __float_as_int(f);
    return (b >= 0) ? ((unsigned)b ^ 0x80000000u) : ~(unsigned)b;
}
__device__ __forceinline__ float ford_inv(unsigned int u) {
    int b = (u & 0x80000000u) ? (int)(u ^ 0x80000000u) : (int)~u;
    return __int_as_float(b);
}

// Phase 1 (r0-verified structure, packed-FP32 inner loop):
//  - candidates staged SoA so {k,k+1} components load as float2 -> the two
//    distances cost 3 v_pk_fma_f32 instead of 6 v_fma_f32; merge keeps the
//    verified v_min3 (value-only, exact), so subtile-base / tie logic and the
//    bit-exact recovery chain are unchanged.
//  - NO fences, NO cross-block signaling (r2/r4 lesson: per-block agent fences
//    serialize the per-XCD L2s, 6x slowdown). atomicMin only, as in r0.
//  - out=0 folded into block 0 (saves the d_out memset dispatch).
__global__ __launch_bounds__(BLK) void nn_min_dual(
    const float* __restrict__ p, const float* __restrict__ g,
    ull* __restrict__ rowmin, ull* __restrict__ colmin,
    float* __restrict__ out, int rowBlocks, int rowSlices, int colSlices)
{
    __shared__ float sbx[SLICE], sby[SLICE], sbz[SLICE], sbw[SLICE];

    if (blockIdx.x == 0 && threadIdx.x == 0) *out = 0.0f;   // fold memset(d_out)

    const float* A; const float* B; ull* outmin; int id, nSlices;
    if ((int)blockIdx.x < rowBlocks) {
        id = blockIdx.x;             A = p; B = g; outmin = rowmin; nSlices = rowSlices;
    } else {
        id = blockIdx.x - rowBlocks; A = g; B = p; outmin = colmin; nSlices = colSlices;
    }
    const int chunk = id / nSlices;
    const int slice = id - chunk * nSlices;
    const int s0 = slice * SLICE;

    // Stage slice SoA (coords + |B|^2). Explicit fmaf: finalize recomputes the
    // identical expression so bit-exact equality holds.
    if (threadIdx.x < SLICE) {
        int s = s0 + threadIdx.x;
        float bx = B[3 * s], by = B[3 * s + 1], bz = B[3 * s + 2];
        float w = fmaf(bz, bz, fmaf(by, by, bx * bx));
        sbx[threadIdx.x] = bx; sby[threadIdx.x] = by;
        sbz[threadIdx.x] = bz; sbw[threadIdx.x] = w;
    }

    const int o0 = chunk * OWNERS + threadIdx.x;
    v2f ax2[IPT], ay2[IPT], az2[IPT];      // splats built ONCE (outside k-loop)
    float best[IPT];
    int base[IPT];
#pragma unroll
    for (int r = 0; r < IPT; ++r) {
        int o = o0 + r * BLK;
        float axv = -2.0f * A[3 * o];
        float ayv = -2.0f * A[3 * o + 1];
        float azv = -2.0f * A[3 * o + 2];
        ax2[r] = (v2f){axv, axv};
        ay2[r] = (v2f){ayv, ayv};
        az2[r] = (v2f){azv, azv};
        best[r] = FLT_MAX;
        base[r] = s0;
    }
    __syncthreads();

    for (int st = 0; st < SLICE; st += SUB) {
        float prev[IPT];
#pragma unroll
        for (int r = 0; r < IPT; ++r) prev[r] = best[r];
#pragma unroll 2
        for (int k = st; k < st + SUB; k += 2) {
            v2f qx = *(const v2f*)&sbx[k];   // k even -> 8B aligned, conflict-free
            v2f qy = *(const v2f*)&sby[k];
            v2f qz = *(const v2f*)&sbz[k];
            v2f qw = *(const v2f*)&sbw[k];
#pragma unroll
            for (int r = 0; r < IPT; ++r) {
                v2f t = fma2(az2[r], qz, qw);       // 3 pk_fma = both candidates
                t = fma2(ay2[r], qy, t);
                t = fma2(ax2[r], qx, t);
                best[r] = fminf(fminf(t.x, t.y), best[r]);   // -> v_min3_f32
            }
        }
#pragma unroll
        for (int r = 0; r < IPT; ++r)
            if (best[r] < prev[r]) base[r] = s0 + st;   // strict <: first subtile wins
    }

#pragma unroll
    for (int r = 0; r < IPT; ++r) {
        ull packed = ((ull)ford(best[r]) << 32) | (unsigned)base[r];
        atomicMin(&outmin[o0 + r * BLK], packed);
    }
}

// Phase 2: owner-per-thread branchless bit-exact rescan (verified absmax=0),
// now at 640 one-wave blocks (vs 160x256: 4x the block spread -> all CUs busy,
// 192 independent cached loads/thread hide latency). One atomicAdd per wave.
__global__ __launch_bounds__(FBLK) void finalize_kernel(
    const ull* __restrict__ rowmin, const ull* __restrict__ colmin,
    const float* __restrict__ p, const float* __restrict__ g,
    const float* __restrict__ pn, const float* __restrict__ gn,
    float* __restrict__ out, int N, int M, float invN, float invM)
{
    int t = blockIdx.x * FBLK + threadIdx.x;
    float c = 0.0f;
    if (t < N + M) {
        const float* A; const float* B; const float* An; const float* Bn;
        ull packed; int o; float inv;
        if (t < N) { o = t;     A = p; B = g; An = pn; Bn = gn; packed = rowmin[o]; inv = invN; }
        else       { o = t - N; A = g; B = p; An = gn; Bn = pn; packed = colmin[o]; inv = invM; }

        float ax = -2.0f * A[3 * o];
        float ay = -2.0f * A[3 * o + 1];
        float az = -2.0f * A[3 * o + 2];
        float bestf = ford_inv((unsigned int)(packed >> 32));
        int b0 = (int)(packed & 0xffffffffull);

        // Branchless first-match: loads stay pipelined (no dependent break).
        int idx = 0x7fffffff;
#pragma unroll 4
        for (int jj = 0; jj < SUB; ++jj) {
            int s = b0 + jj;
            float bx = B[3 * s], by = B[3 * s + 1], bz = B[3 * s + 2];
            float w = fmaf(bz, bz, fmaf(by, by, bx * bx));
            float v = fmaf(ax, bx, fmaf(ay, by, fmaf(az, bz, w)));
            int cand = (v == bestf) ? s : 0x7fffffff;
            idx = (cand < idx) ? cand : idx;     // ascending -> first match = min s
        }
        if (idx == 0x7fffffff) idx = b0;         // defensive; cannot trigger

        float d = An[3 * o] * Bn[3 * idx] + An[3 * o + 1] * Bn[3 * idx + 1]
                + An[3 * o + 2] * Bn[3 * idx + 2];
        c = (1.0f - d) * inv;
    }
#pragma unroll
    for (int off = 32; off > 0; off >>= 1) c += __shfl_down(c, off, 64);
    if (threadIdx.x == 0) atomicAdd(out, c);
}

extern "C" void kernel_launch(void* const* d_in, const int* in_sizes, int n_in,
                              void* d_out, int out_size, void* d_ws, size_t ws_size,
                              hipStream_t stream) {
    const float* p  = (const float*)d_in[0];   // [N,3] predicted points
    const float* pn = (const float*)d_in[1];   // [N,3] predicted normals (unit)
    const float* g  = (const float*)d_in[2];   // [M,3] gt points
    const float* gn = (const float*)d_in[3];   // [M,3] gt normals (unit)
    const int N = in_sizes[0] / 3;             // 8192
    const int M = in_sizes[2] / 3;             // 32768
    float* out = (float*)d_out;

    ull* rowmin = (ull*)d_ws;                  // [N]
    ull* colmin = rowmin + N;                  // [M]

    // 3 dispatches: 320 KB memset + phase-1 (zeroes out) + finalize.
    hipMemsetAsync(d_ws, 0xFF, (size_t)(N + M) * sizeof(ull), stream);

    const int rowSlices = M / SLICE;                 // 256
    const int colSlices = N / SLICE;                 // 64
    const int rowBlocks = (N / OWNERS) * rowSlices;  // 4*256  = 1024
    const int colBlocks = (M / OWNERS) * colSlices;  // 16*64  = 1024
    nn_min_dual<<<rowBlocks + colBlocks, BLK, 0, stream>>>(
        p, g, rowmin, colmin, out, rowBlocks, rowSlices, colSlices);

    const int tot = N + M;                           // 40960
    finalize_kernel<<<(tot + FBLK - 1) / FBLK, FBLK, 0, stream>>>(
        rowmin, colmin, p, g, pn, gn, out, N, M, 1.0f / N, 1.0f / M);
}